// Round 10
// baseline (2430.576 us; speedup 1.0000x reference)
//
#include <hip/hip_runtime.h>
#include <hip/hip_bf16.h>

typedef __attribute__((ext_vector_type(8))) short bf16x8;
typedef __attribute__((ext_vector_type(4))) float f32x4;

#define NBATCH 4096
#define SEQT 181
#define NFEAT 12
#define HDIM 128
#define ROWS 16
#define LSTR 136              // padded bf16 row stride for activations
#define OUTSTRIDE (SEQT*NFEAT)

// d_ws layout (same as R1..R9):
#define WFRAG_ELEMS 262144
#define WOUT_ELEMS  4096
#define BIAS_F32OFF (532480/4)
#define BOUT_F32OFF (536576/4)

// LDS byte offsets: [0,131072) weight tail frags (s=6,7); act 6 bufs; bout
#define ACT_OFF  131072
#define BIAS_OFF 157184      // (unused by cells now; bias lives in 4 VGPRs)
#define BOUT_OFF 161280
#define SMEM_BYTES 161344

__device__ __forceinline__ float fsig(float x) {
  return __builtin_amdgcn_rcpf(1.0f + __builtin_amdgcn_exp2f(-1.442695041f * x));
}
__device__ __forceinline__ float ftanh(float x) {
  float e = __builtin_amdgcn_exp2f(-2.885390082f * x);   // = exp(-2x)
  return __builtin_fmaf(2.0f, __builtin_amdgcn_rcpf(1.0f + e), -1.0f);
}
__device__ __forceinline__ unsigned short f2bf(float x) {
  __hip_bfloat16 h = __float2bfloat16(x);
  return __builtin_bit_cast(unsigned short, h);
}

// ---------------- setup: repack weights into MFMA fragment order (bf16) ----------------
__global__ void setup_kernel(const float* __restrict__ Wih0, const float* __restrict__ Whh0,
                             const float* __restrict__ bih0, const float* __restrict__ bhh0,
                             const float* __restrict__ Wih1, const float* __restrict__ Whh1,
                             const float* __restrict__ bih1, const float* __restrict__ bhh1,
                             const float* __restrict__ Wo,   const float* __restrict__ bo,
                             unsigned short* __restrict__ ws)
{
  int idx = blockIdx.x * blockDim.x + threadIdx.x;
  if (idx < WFRAG_ELEMS) {
    // A-frag (weights): lane&15 = gate-dim, k=(lane>>4)*8+e over [x(128)|h(128)]
    int e = idx & 7, lane = (idx >> 3) & 63, s = (idx >> 9) & 7, g = (idx >> 12) & 3,
        w = (idx >> 14) & 7, l = idx >> 17;
    int row = g * 128 + w * 16 + (lane & 15);
    int k   = s * 32 + (lane >> 4) * 8 + e;
    const float* Wih = l ? Wih1 : Wih0;
    const float* Whh = l ? Whh1 : Whh0;
    float v = (k < HDIM) ? Wih[row * HDIM + k] : Whh[row * HDIM + (k - HDIM)];
    ws[idx] = f2bf(v);
  } else if (idx < WFRAG_ELEMS + WOUT_ELEMS) {
    int i2 = idx - WFRAG_ELEMS;
    int e = i2 & 7, lane = (i2 >> 3) & 63, s = i2 >> 9;
    int c = lane & 15;
    int k = s * 32 + (lane >> 4) * 8 + e;           // k over [z0(128) | z1(128)]
    float v = (c < NFEAT) ? Wo[c * 256 + k] : 0.0f;
    ws[idx] = f2bf(v);
  } else if (idx < WFRAG_ELEMS + WOUT_ELEMS + 1024) {
    int i3 = idx - (WFRAG_ELEMS + WOUT_ELEMS);
    int l = i3 >> 9, r = i3 & 511;
    float v = l ? (bih1[r] + bhh1[r]) : (bih0[r] + bhh0[r]);
    reinterpret_cast<float*>(ws)[BIAS_F32OFF + i3] = v;
  } else if (idx < WFRAG_ELEMS + WOUT_ELEMS + 1024 + 16) {
    int i4 = idx - (WFRAG_ELEMS + WOUT_ELEMS + 1024);
    reinterpret_cast<float*>(ws)[BOUT_F32OFF + i4] = (i4 < NFEAT) ? bo[i4] : 0.0f;
  }
}

// ---------------- main: 256 blocks x 512 threads ------------------------------------
// R10 = R8 structure (known-good, zero spill) + bias moved from LDS (4 b128
// reads/cell/wave) into 4 persistent bf16x8 VGPRs unpacked by 16 VALU ops.
// Cuts per-cell LDS reads 20 -> 16 (the LDS pipe is the throughput floor).
// R9's cross-barrier prefetch (+24 regs) re-triggered the weight spill; this
// adds only +4 persistent regs and no cross-barrier live state.
__global__ void
__attribute__((amdgpu_flat_work_group_size(512, 512), amdgpu_waves_per_eu(2, 2)))
lstm_kernel(
    const float* __restrict__ ench, const float* __restrict__ encc,
    const unsigned short* __restrict__ wfrag, const unsigned short* __restrict__ woutf,
    const float* __restrict__ biasc, const float* __restrict__ boutc,
    float* __restrict__ out)
{
  __shared__ __align__(16) unsigned char smem[SMEM_BYTES];
  bf16x8* wlds = reinterpret_cast<bf16x8*>(smem);
  unsigned short* act = reinterpret_cast<unsigned short*>(smem + ACT_OFF);

  const int tid  = threadIdx.x;
  const int wave = tid >> 6, lane = tid & 63;
  const int col  = lane & 15, lg = lane >> 4;
  const int n0   = blockIdx.x * ROWS;
  const int dbase = wave * 16 + lg * 4;

  const bf16x8* wfv = reinterpret_cast<const bf16x8*>(wfrag);

  // ---- persistent weight fragments: s=0..5 in registers (pinned chunk-by-chunk,
  //      fenced so the scheduler can't cluster all 48 loads into one pressure spike)
  bf16x8 wreg[2][4][6];
  #pragma unroll
  for (int l = 0; l < 2; ++l)
    #pragma unroll
    for (int g = 0; g < 4; ++g) {
      #pragma unroll
      for (int s = 0; s < 6; ++s)
        wreg[l][g][s] = wfv[(size_t)((((l * 8 + wave) * 4 + g) * 8) + s) * 64 + lane];
      #pragma unroll
      for (int s = 0; s < 6; ++s) {
        f32x4 t_ = __builtin_bit_cast(f32x4, wreg[l][g][s]);
        asm volatile("" : "+v"(t_));            // opaque: no remat, value must stay live
        wreg[l][g][s] = __builtin_bit_cast(bf16x8, t_);
      }
      __builtin_amdgcn_sched_barrier(0);        // fence: next chunk can't be hoisted up
    }

  // ---- s=6..7 fragments -> LDS (16/wave, 128 KiB total) ----
  #pragma unroll
  for (int l = 0; l < 2; ++l)
    #pragma unroll
    for (int g = 0; g < 4; ++g)
      #pragma unroll
      for (int si = 0; si < 2; ++si)
        wlds[(((wave * 2 + l) * 4 + g) * 2 + si) * 64 + lane] =
            wfv[(size_t)((((l * 8 + wave) * 4 + g) * 8) + 6 + si) * 64 + lane];

  // ---- persistent bias: 32 bf16 in 4 regs. breg[l][gp] = gates 2gp,2gp+1 (4 dims each)
  bf16x8 breg[2][2];
  #pragma unroll
  for (int l = 0; l < 2; ++l)
    #pragma unroll
    for (int gp = 0; gp < 2; ++gp) {
      f32x4 u = *reinterpret_cast<const f32x4*>(&biasc[l * 512 + (2 * gp) * 128 + dbase]);
      f32x4 v = *reinterpret_cast<const f32x4*>(&biasc[l * 512 + (2 * gp + 1) * 128 + dbase]);
      bf16x8 r;
      r[0] = (short)f2bf(u[0]); r[1] = (short)f2bf(u[1]);
      r[2] = (short)f2bf(u[2]); r[3] = (short)f2bf(u[3]);
      r[4] = (short)f2bf(v[0]); r[5] = (short)f2bf(v[1]);
      r[6] = (short)f2bf(v[2]); r[7] = (short)f2bf(v[3]);
      breg[l][gp] = r;
    }

  // zero x-ping buffers 0,1 (dec_in0 = 0)
  for (int i = tid; i < 2 * ROWS * LSTR; i += 512) act[i] = 0;
  // initial h layer0 -> buf5 ; initial h layer1 -> buf3 (read once by L1t0 at t=0,
  // then overwritten by L1t1(t=0) which runs after that read -- no race)
  for (int i = tid; i < ROWS * HDIM; i += 512) {
    int r = i >> 7, d = i & (HDIM - 1);
    act[(5 * ROWS + r) * LSTR + d] = f2bf(ench[(n0 + r) * HDIM + d]);
    act[(3 * ROWS + r) * LSTR + d] = f2bf(ench[(size_t)(NBATCH + n0 + r) * HDIM + d]);
  }
  if (tid < 16) reinterpret_cast<float*>(smem + BOUT_OFF)[tid] = boutc[tid];
  // c-state: lane holds batch n0+col, dims dbase..dbase+3
  f32x4 c0 = *reinterpret_cast<const f32x4*>(&encc[(size_t)(n0 + col) * HDIM + dbase]);
  f32x4 c1 = *reinterpret_cast<const f32x4*>(&encc[(size_t)(NBATCH + n0 + col) * HDIM + dbase]);
  __syncthreads();

  const int aoffl = col * LSTR + lg * 8;

  // unpack one bf16x8 half (4 values) to f32x4: f32bits = bf16bits << 16 (exact)
  auto bini = [&](const bf16x8& br, int half) -> f32x4 {
    f32x4 r;
    #pragma unroll
    for (int j = 0; j < 4; ++j) {
      unsigned u = ((unsigned)(unsigned short)br[half * 4 + j]) << 16;
      r[j] = __builtin_bit_cast(float, u);
    }
    return r;
  };

  // streamed cell: one B-fragment ds_read at a time -> 4 MFMAs; bias from regs.
  auto cell = [&](int xb, int hb, int ob, const bf16x8 (&wr)[4][6], int lb, int bl, f32x4& c) {
    const unsigned short* xp = act + xb * (ROWS * LSTR) + aoffl;
    const unsigned short* hp = act + hb * (ROWS * LSTR) + aoffl;
    f32x4 acc0 = bini(breg[bl][0], 0);
    f32x4 acc1 = bini(breg[bl][0], 1);
    f32x4 acc2 = bini(breg[bl][1], 0);
    f32x4 acc3 = bini(breg[bl][1], 1);
    #pragma unroll
    for (int s = 0; s < 4; ++s) {                       // k = x-half (reg weights)
      bf16x8 b = *reinterpret_cast<const bf16x8*>(&xp[s * 32]);
      acc0 = __builtin_amdgcn_mfma_f32_16x16x32_bf16(wr[0][s], b, acc0, 0, 0, 0);
      acc1 = __builtin_amdgcn_mfma_f32_16x16x32_bf16(wr[1][s], b, acc1, 0, 0, 0);
      acc2 = __builtin_amdgcn_mfma_f32_16x16x32_bf16(wr[2][s], b, acc2, 0, 0, 0);
      acc3 = __builtin_amdgcn_mfma_f32_16x16x32_bf16(wr[3][s], b, acc3, 0, 0, 0);
    }
    #pragma unroll
    for (int s = 0; s < 2; ++s) {                       // k = h-half, reg weights
      bf16x8 b = *reinterpret_cast<const bf16x8*>(&hp[s * 32]);
      acc0 = __builtin_amdgcn_mfma_f32_16x16x32_bf16(wr[0][4 + s], b, acc0, 0, 0, 0);
      acc1 = __builtin_amdgcn_mfma_f32_16x16x32_bf16(wr[1][4 + s], b, acc1, 0, 0, 0);
      acc2 = __builtin_amdgcn_mfma_f32_16x16x32_bf16(wr[2][4 + s], b, acc2, 0, 0, 0);
      acc3 = __builtin_amdgcn_mfma_f32_16x16x32_bf16(wr[3][4 + s], b, acc3, 0, 0, 0);
    }
    #pragma unroll
    for (int si = 0; si < 2; ++si) {                    // k = h-half tail, LDS weights
      bf16x8 b = *reinterpret_cast<const bf16x8*>(&hp[(2 + si) * 32]);
      bf16x8 w0 = wlds[(lb + 0 * 2 + si) * 64 + lane];
      bf16x8 w1 = wlds[(lb + 1 * 2 + si) * 64 + lane];
      bf16x8 w2 = wlds[(lb + 2 * 2 + si) * 64 + lane];
      bf16x8 w3 = wlds[(lb + 3 * 2 + si) * 64 + lane];
      acc0 = __builtin_amdgcn_mfma_f32_16x16x32_bf16(w0, b, acc0, 0, 0, 0);
      acc1 = __builtin_amdgcn_mfma_f32_16x16x32_bf16(w1, b, acc1, 0, 0, 0);
      acc2 = __builtin_amdgcn_mfma_f32_16x16x32_bf16(w2, b, acc2, 0, 0, 0);
      acc3 = __builtin_amdgcn_mfma_f32_16x16x32_bf16(w3, b, acc3, 0, 0, 0);
    }
    // gates: i,f,g,o ; lane: batch col, dims dbase..dbase+3
    float cn0 = fsig(acc1[0]) * c[0] + fsig(acc0[0]) * ftanh(acc2[0]);
    float cn1 = fsig(acc1[1]) * c[1] + fsig(acc0[1]) * ftanh(acc2[1]);
    float cn2 = fsig(acc1[2]) * c[2] + fsig(acc0[2]) * ftanh(acc2[2]);
    float cn3 = fsig(acc1[3]) * c[3] + fsig(acc0[3]) * ftanh(acc2[3]);
    c[0] = cn0; c[1] = cn1; c[2] = cn2; c[3] = cn3;
    unsigned int h0 = f2bf(fsig(acc3[0]) * ftanh(cn0));
    unsigned int h1 = f2bf(fsig(acc3[1]) * ftanh(cn1));
    unsigned int h2 = f2bf(fsig(acc3[2]) * ftanh(cn2));
    unsigned int h3 = f2bf(fsig(acc3[3]) * ftanh(cn3));
    uint2* op = reinterpret_cast<uint2*>(act + ob * (ROWS * LSTR) + col * LSTR + dbase);
    *op = make_uint2(h0 | (h1 << 16), h2 | (h3 << 16));
    __syncthreads();
  };

  const int lb0 = (wave * 2 + 0) * 8;
  const int lb1 = (wave * 2 + 1) * 8;
  const bf16x8* wov = reinterpret_cast<const bf16x8*>(woutf);

  for (int t = 0; t < SEQT; ++t) {
    const int xA = (t & 1) ? 2 : 0, xB = xA + 1;
    const int zA = (t & 1) ? 0 : 2, zB = zA + 1;
    cell(xA, 5, 4, wreg[0], lb0, 0, c0);               // L0 t0
    cell(xB, 4, 5, wreg[0], lb0, 0, c0);               // L0 t1
    cell(4, (t == 0) ? 3 : xB, zA, wreg[1], lb1, 1, c1); // L1 t0 (t=0: h1 staged in buf3)
    cell(5, zA, zB, wreg[1], lb1, 1, c1);              // L1 t1
    if (wave == 0) {                                   // output projection (one tile)
      const unsigned short* z0 = act + zA * (ROWS * LSTR) + aoffl;
      const unsigned short* z1 = act + zB * (ROWS * LSTR) + aoffl;
      f32x4 po = *reinterpret_cast<const f32x4*>(smem + BOUT_OFF + lg * 16);
      #pragma unroll
      for (int s = 0; s < 4; ++s) {
        bf16x8 z = *reinterpret_cast<const bf16x8*>(&z0[s * 32]);
        po = __builtin_amdgcn_mfma_f32_16x16x32_bf16(wov[s * 64 + lane], z, po, 0, 0, 0);
      }
      #pragma unroll
      for (int s = 0; s < 4; ++s) {
        bf16x8 z = *reinterpret_cast<const bf16x8*>(&z1[s * 32]);
        po = __builtin_amdgcn_mfma_f32_16x16x32_bf16(wov[(4 + s) * 64 + lane], z, po, 0, 0, 0);
      }
      if (lg < 3) {
        f32x4 r;
        r[0] = fsig(po[0]); r[1] = fsig(po[1]); r[2] = fsig(po[2]); r[3] = fsig(po[3]);
        *reinterpret_cast<f32x4*>(&out[(size_t)(n0 + col) * OUTSTRIDE + t * NFEAT + lg * 4]) = r;
      }
    }
  }
}

extern "C" void kernel_launch(void* const* d_in, const int* in_sizes, int n_in,
                              void* d_out, int out_size, void* d_ws, size_t ws_size,
                              hipStream_t stream) {
  const float* ench = (const float*)d_in[0];
  const float* encc = (const float*)d_in[1];
  const float* Wih0 = (const float*)d_in[2];
  const float* Whh0 = (const float*)d_in[3];
  const float* bih0 = (const float*)d_in[4];
  const float* bhh0 = (const float*)d_in[5];
  const float* Wih1 = (const float*)d_in[6];
  const float* Whh1 = (const float*)d_in[7];
  const float* bih1 = (const float*)d_in[8];
  const float* bhh1 = (const float*)d_in[9];
  const float* Wo   = (const float*)d_in[10];
  const float* bo   = (const float*)d_in[11];
  unsigned short* ws = (unsigned short*)d_ws;

  int total = WFRAG_ELEMS + WOUT_ELEMS + 1024 + 16;
  int blocks = (total + 511) / 512;
  hipLaunchKernelGGL(setup_kernel, dim3(blocks), dim3(512), 0, stream,
                     Wih0, Whh0, bih0, bhh0, Wih1, Whh1, bih1, bhh1, Wo, bo, ws);

  const unsigned short* wfrag = ws;
  const unsigned short* woutf = ws + WFRAG_ELEMS;
  const float* biasc = reinterpret_cast<const float*>(ws) + BIAS_F32OFF;
  const float* boutc = reinterpret_cast<const float*>(ws) + BOUT_F32OFF;

  hipLaunchKernelGGL(lstm_kernel, dim3(NBATCH / ROWS), dim3(512), 0, stream,
                     ench, encc, wfrag, woutf, biasc, boutc, (float*)d_out);
}

// Round 11
// 860.994 us; speedup vs baseline: 2.8230x; 2.8230x over previous
//
#include <hip/hip_runtime.h>
#include <hip/hip_bf16.h>

typedef __attribute__((ext_vector_type(8))) short bf16x8;
typedef __attribute__((ext_vector_type(4))) float f32x4;

#define NBATCH 4096
#define SEQT 181
#define NFEAT 12
#define HDIM 128
#define ROWS 16
#define LSTR 136              // padded bf16 row stride for activations
#define OUTSTRIDE (SEQT*NFEAT)

// d_ws layout (ushort units):
#define WFRAG_ELEMS 262144
#define WOUT_ELEMS  4096
#define BIAS_F32OFF (532480/4)     // f32 index (legacy, unused by cells)
#define BOUT_F32OFF (536576/4)     // f32 index
#define BBF16_U16OFF 268320        // bf16-packed bias [l][wave][lg][16]

// LDS byte offsets: [0,131072) weight tail frags (s=6,7); act 6 bufs; bias bf16; bout
#define ACT_OFF  131072
#define BIAS_OFF 157184            // 2KB used (bf16-packed bias)
#define BOUT_OFF 161280
#define SMEM_BYTES 161344

// fast barrier: LDS-visibility only (skip vmcnt drain -- wave0's out-proj
// global ops need no cross-wave ordering; hardware retires stores on its own)
#define FBAR() asm volatile("s_waitcnt lgkmcnt(0)\n\ts_barrier" ::: "memory")

__device__ __forceinline__ float fsig(float x) {
  return __builtin_amdgcn_rcpf(1.0f + __builtin_amdgcn_exp2f(-1.442695041f * x));
}
__device__ __forceinline__ float ftanh(float x) {
  float e = __builtin_amdgcn_exp2f(-2.885390082f * x);   // = exp(-2x)
  return __builtin_fmaf(2.0f, __builtin_amdgcn_rcpf(1.0f + e), -1.0f);
}
__device__ __forceinline__ unsigned short f2bf(float x) {
  __hip_bfloat16 h = __float2bfloat16(x);
  return __builtin_bit_cast(unsigned short, h);
}

// ---------------- setup: repack weights into MFMA fragment order (bf16) ----------------
__global__ void setup_kernel(const float* __restrict__ Wih0, const float* __restrict__ Whh0,
                             const float* __restrict__ bih0, const float* __restrict__ bhh0,
                             const float* __restrict__ Wih1, const float* __restrict__ Whh1,
                             const float* __restrict__ bih1, const float* __restrict__ bhh1,
                             const float* __restrict__ Wo,   const float* __restrict__ bo,
                             unsigned short* __restrict__ ws)
{
  int idx = blockIdx.x * blockDim.x + threadIdx.x;
  if (idx < WFRAG_ELEMS) {
    // A-frag (weights): lane&15 = gate-dim, k=(lane>>4)*8+e over [x(128)|h(128)]
    int e = idx & 7, lane = (idx >> 3) & 63, s = (idx >> 9) & 7, g = (idx >> 12) & 3,
        w = (idx >> 14) & 7, l = idx >> 17;
    int row = g * 128 + w * 16 + (lane & 15);
    int k   = s * 32 + (lane >> 4) * 8 + e;
    const float* Wih = l ? Wih1 : Wih0;
    const float* Whh = l ? Whh1 : Whh0;
    float v = (k < HDIM) ? Wih[row * HDIM + k] : Whh[row * HDIM + (k - HDIM)];
    ws[idx] = f2bf(v);
  } else if (idx < WFRAG_ELEMS + WOUT_ELEMS) {
    int i2 = idx - WFRAG_ELEMS;
    int e = i2 & 7, lane = (i2 >> 3) & 63, s = i2 >> 9;
    int c = lane & 15;
    int k = s * 32 + (lane >> 4) * 8 + e;           // k over [z0(128) | z1(128)]
    float v = (c < NFEAT) ? Wo[c * 256 + k] : 0.0f;
    ws[idx] = f2bf(v);
  } else if (idx < WFRAG_ELEMS + WOUT_ELEMS + 1024) {
    int i3 = idx - (WFRAG_ELEMS + WOUT_ELEMS);
    int l = i3 >> 9, r = i3 & 511;
    float v = l ? (bih1[r] + bhh1[r]) : (bih0[r] + bhh0[r]);
    reinterpret_cast<float*>(ws)[BIAS_F32OFF + i3] = v;
  } else if (idx < WFRAG_ELEMS + WOUT_ELEMS + 1024 + 16) {
    int i4 = idx - (WFRAG_ELEMS + WOUT_ELEMS + 1024);
    reinterpret_cast<float*>(ws)[BOUT_F32OFF + i4] = (i4 < NFEAT) ? bo[i4] : 0.0f;
  } else if (idx < WFRAG_ELEMS + WOUT_ELEMS + 1024 + 16 + 1024) {
    // bf16-packed bias: [l][wave][lg][16] ; ushort j16: f=j16>>3 (gate pair),
    // j=j16&7: gate = 2f + (j>>2), dim = wave*16 + lg*4 + (j&3)
    int i5 = idx - (WFRAG_ELEMS + WOUT_ELEMS + 1024 + 16);
    int l = i5 >> 9, r = i5 & 511;
    int w = r >> 6, lg = (r >> 4) & 3, j16 = r & 15;
    int f = j16 >> 3, j = j16 & 7;
    int gate = f * 2 + (j >> 2);
    int dim  = w * 16 + lg * 4 + (j & 3);
    float v = l ? (bih1[gate * 128 + dim] + bhh1[gate * 128 + dim])
                : (bih0[gate * 128 + dim] + bhh0[gate * 128 + dim]);
    ws[BBF16_U16OFF + i5] = f2bf(v);
  }
}

// ---------------- main: 256 blocks x 512 threads ------------------------------------
// R11 = R8 (known-good, zero spill) + (a) bias as 2 bf16 b128 LDS reads unpacked
// into acc via shifts (cell LDS reads 20 -> 18; zero persistent regs added) and
// (b) lgkm-only fast barrier (skips vmcnt drain of wave0's out-proj global ops).
__global__ void
__attribute__((amdgpu_flat_work_group_size(512, 512), amdgpu_waves_per_eu(2, 2)))
lstm_kernel(
    const float* __restrict__ ench, const float* __restrict__ encc,
    const unsigned short* __restrict__ wfrag, const unsigned short* __restrict__ woutf,
    const unsigned short* __restrict__ biasbf, const float* __restrict__ boutc,
    float* __restrict__ out)
{
  __shared__ __align__(16) unsigned char smem[SMEM_BYTES];
  bf16x8* wlds = reinterpret_cast<bf16x8*>(smem);
  unsigned short* act = reinterpret_cast<unsigned short*>(smem + ACT_OFF);

  const int tid  = threadIdx.x;
  const int wave = tid >> 6, lane = tid & 63;
  const int col  = lane & 15, lg = lane >> 4;
  const int n0   = blockIdx.x * ROWS;
  const int dbase = wave * 16 + lg * 4;

  const bf16x8* wfv = reinterpret_cast<const bf16x8*>(wfrag);

  // ---- persistent weight fragments: s=0..5 in registers (pinned chunk-by-chunk,
  //      fenced so the scheduler can't cluster all 48 loads into one pressure spike)
  bf16x8 wreg[2][4][6];
  #pragma unroll
  for (int l = 0; l < 2; ++l)
    #pragma unroll
    for (int g = 0; g < 4; ++g) {
      #pragma unroll
      for (int s = 0; s < 6; ++s)
        wreg[l][g][s] = wfv[(size_t)((((l * 8 + wave) * 4 + g) * 8) + s) * 64 + lane];
      #pragma unroll
      for (int s = 0; s < 6; ++s) {
        f32x4 t_ = __builtin_bit_cast(f32x4, wreg[l][g][s]);
        asm volatile("" : "+v"(t_));            // opaque: no remat, value must stay live
        wreg[l][g][s] = __builtin_bit_cast(bf16x8, t_);
      }
      __builtin_amdgcn_sched_barrier(0);        // fence: next chunk can't be hoisted up
    }

  // ---- s=6..7 fragments -> LDS (16/wave, 128 KiB total) ----
  #pragma unroll
  for (int l = 0; l < 2; ++l)
    #pragma unroll
    for (int g = 0; g < 4; ++g)
      #pragma unroll
      for (int si = 0; si < 2; ++si)
        wlds[(((wave * 2 + l) * 4 + g) * 2 + si) * 64 + lane] =
            wfv[(size_t)((((l * 8 + wave) * 4 + g) * 8) + 6 + si) * 64 + lane];

  // zero x-ping buffers 0,1 (dec_in0 = 0)
  for (int i = tid; i < 2 * ROWS * LSTR; i += 512) act[i] = 0;
  // initial h layer0 -> buf5 ; initial h layer1 -> buf3 (read once by L1t0 at t=0,
  // then overwritten by L1t1(t=0) which runs after that read -- no race)
  for (int i = tid; i < ROWS * HDIM; i += 512) {
    int r = i >> 7, d = i & (HDIM - 1);
    act[(5 * ROWS + r) * LSTR + d] = f2bf(ench[(n0 + r) * HDIM + d]);
    act[(3 * ROWS + r) * LSTR + d] = f2bf(ench[(size_t)(NBATCH + n0 + r) * HDIM + d]);
  }
  // bf16-packed bias -> LDS (1024 ushorts = 2KB)
  for (int i = tid; i < 1024; i += 512)
    reinterpret_cast<unsigned short*>(smem + BIAS_OFF)[i] = biasbf[i];
  if (tid < 16) reinterpret_cast<float*>(smem + BOUT_OFF)[tid] = boutc[tid];
  // c-state: lane holds batch n0+col, dims dbase..dbase+3
  f32x4 c0 = *reinterpret_cast<const f32x4*>(&encc[(size_t)(n0 + col) * HDIM + dbase]);
  f32x4 c1 = *reinterpret_cast<const f32x4*>(&encc[(size_t)(NBATCH + n0 + col) * HDIM + dbase]);
  __syncthreads();   // init barrier: full drain (global staging must be visible)

  const int aoffl = col * LSTR + lg * 8;

  // streamed cell: one B-fragment ds_read at a time -> 4 MFMAs; bias from 2
  // broadcast b128 LDS reads unpacked into acc (bf16<<16 = exact f32).
  auto cell = [&](int xb, int hb, int ob, const bf16x8 (&wr)[4][6], int lb, int bl, f32x4& c) {
    const unsigned short* xp = act + xb * (ROWS * LSTR) + aoffl;
    const unsigned short* hp = act + hb * (ROWS * LSTR) + aoffl;
    const unsigned char* bptr = smem + BIAS_OFF + (size_t)(((bl * 8 + wave) * 4 + lg) * 32);
    bf16x8 bb0 = *reinterpret_cast<const bf16x8*>(bptr);
    bf16x8 bb1 = *reinterpret_cast<const bf16x8*>(bptr + 16);
    f32x4 acc0, acc1, acc2, acc3;
    #pragma unroll
    for (int j = 0; j < 4; ++j) {
      acc0[j] = __builtin_bit_cast(float, ((unsigned)(unsigned short)bb0[j]) << 16);
      acc1[j] = __builtin_bit_cast(float, ((unsigned)(unsigned short)bb0[4 + j]) << 16);
      acc2[j] = __builtin_bit_cast(float, ((unsigned)(unsigned short)bb1[j]) << 16);
      acc3[j] = __builtin_bit_cast(float, ((unsigned)(unsigned short)bb1[4 + j]) << 16);
    }
    #pragma unroll
    for (int s = 0; s < 4; ++s) {                       // k = x-half (reg weights)
      bf16x8 b = *reinterpret_cast<const bf16x8*>(&xp[s * 32]);
      acc0 = __builtin_amdgcn_mfma_f32_16x16x32_bf16(wr[0][s], b, acc0, 0, 0, 0);
      acc1 = __builtin_amdgcn_mfma_f32_16x16x32_bf16(wr[1][s], b, acc1, 0, 0, 0);
      acc2 = __builtin_amdgcn_mfma_f32_16x16x32_bf16(wr[2][s], b, acc2, 0, 0, 0);
      acc3 = __builtin_amdgcn_mfma_f32_16x16x32_bf16(wr[3][s], b, acc3, 0, 0, 0);
    }
    #pragma unroll
    for (int s = 0; s < 2; ++s) {                       // k = h-half, reg weights
      bf16x8 b = *reinterpret_cast<const bf16x8*>(&hp[s * 32]);
      acc0 = __builtin_amdgcn_mfma_f32_16x16x32_bf16(wr[0][4 + s], b, acc0, 0, 0, 0);
      acc1 = __builtin_amdgcn_mfma_f32_16x16x32_bf16(wr[1][4 + s], b, acc1, 0, 0, 0);
      acc2 = __builtin_amdgcn_mfma_f32_16x16x32_bf16(wr[2][4 + s], b, acc2, 0, 0, 0);
      acc3 = __builtin_amdgcn_mfma_f32_16x16x32_bf16(wr[3][4 + s], b, acc3, 0, 0, 0);
    }
    #pragma unroll
    for (int si = 0; si < 2; ++si) {                    // k = h-half tail, LDS weights
      bf16x8 b = *reinterpret_cast<const bf16x8*>(&hp[(2 + si) * 32]);
      bf16x8 w0 = wlds[(lb + 0 * 2 + si) * 64 + lane];
      bf16x8 w1 = wlds[(lb + 1 * 2 + si) * 64 + lane];
      bf16x8 w2 = wlds[(lb + 2 * 2 + si) * 64 + lane];
      bf16x8 w3 = wlds[(lb + 3 * 2 + si) * 64 + lane];
      acc0 = __builtin_amdgcn_mfma_f32_16x16x32_bf16(w0, b, acc0, 0, 0, 0);
      acc1 = __builtin_amdgcn_mfma_f32_16x16x32_bf16(w1, b, acc1, 0, 0, 0);
      acc2 = __builtin_amdgcn_mfma_f32_16x16x32_bf16(w2, b, acc2, 0, 0, 0);
      acc3 = __builtin_amdgcn_mfma_f32_16x16x32_bf16(w3, b, acc3, 0, 0, 0);
    }
    // gates: i,f,g,o ; lane: batch col, dims dbase..dbase+3
    float cn0 = fsig(acc1[0]) * c[0] + fsig(acc0[0]) * ftanh(acc2[0]);
    float cn1 = fsig(acc1[1]) * c[1] + fsig(acc0[1]) * ftanh(acc2[1]);
    float cn2 = fsig(acc1[2]) * c[2] + fsig(acc0[2]) * ftanh(acc2[2]);
    float cn3 = fsig(acc1[3]) * c[3] + fsig(acc0[3]) * ftanh(acc2[3]);
    c[0] = cn0; c[1] = cn1; c[2] = cn2; c[3] = cn3;
    unsigned int h0 = f2bf(fsig(acc3[0]) * ftanh(cn0));
    unsigned int h1 = f2bf(fsig(acc3[1]) * ftanh(cn1));
    unsigned int h2 = f2bf(fsig(acc3[2]) * ftanh(cn2));
    unsigned int h3 = f2bf(fsig(acc3[3]) * ftanh(cn3));
    uint2* op = reinterpret_cast<uint2*>(act + ob * (ROWS * LSTR) + col * LSTR + dbase);
    *op = make_uint2(h0 | (h1 << 16), h2 | (h3 << 16));
    FBAR();
  };

  const int lb0 = (wave * 2 + 0) * 8;
  const int lb1 = (wave * 2 + 1) * 8;
  const bf16x8* wov = reinterpret_cast<const bf16x8*>(woutf);

  for (int t = 0; t < SEQT; ++t) {
    const int xA = (t & 1) ? 2 : 0, xB = xA + 1;
    const int zA = (t & 1) ? 0 : 2, zB = zA + 1;
    cell(xA, 5, 4, wreg[0], lb0, 0, c0);               // L0 t0
    cell(xB, 4, 5, wreg[0], lb0, 0, c0);               // L0 t1
    cell(4, (t == 0) ? 3 : xB, zA, wreg[1], lb1, 1, c1); // L1 t0 (t=0: h1 staged in buf3)
    cell(5, zA, zB, wreg[1], lb1, 1, c1);              // L1 t1
    if (wave == 0) {                                   // output projection (one tile)
      const unsigned short* z0 = act + zA * (ROWS * LSTR) + aoffl;
      const unsigned short* z1 = act + zB * (ROWS * LSTR) + aoffl;
      f32x4 po = *reinterpret_cast<const f32x4*>(smem + BOUT_OFF + lg * 16);
      #pragma unroll
      for (int s = 0; s < 4; ++s) {
        bf16x8 z = *reinterpret_cast<const bf16x8*>(&z0[s * 32]);
        po = __builtin_amdgcn_mfma_f32_16x16x32_bf16(wov[s * 64 + lane], z, po, 0, 0, 0);
      }
      #pragma unroll
      for (int s = 0; s < 4; ++s) {
        bf16x8 z = *reinterpret_cast<const bf16x8*>(&z1[s * 32]);
        po = __builtin_amdgcn_mfma_f32_16x16x32_bf16(wov[(4 + s) * 64 + lane], z, po, 0, 0, 0);
      }
      if (lg < 3) {
        f32x4 r;
        r[0] = fsig(po[0]); r[1] = fsig(po[1]); r[2] = fsig(po[2]); r[3] = fsig(po[3]);
        *reinterpret_cast<f32x4*>(&out[(size_t)(n0 + col) * OUTSTRIDE + t * NFEAT + lg * 4]) = r;
      }
    }
  }
}

extern "C" void kernel_launch(void* const* d_in, const int* in_sizes, int n_in,
                              void* d_out, int out_size, void* d_ws, size_t ws_size,
                              hipStream_t stream) {
  const float* ench = (const float*)d_in[0];
  const float* encc = (const float*)d_in[1];
  const float* Wih0 = (const float*)d_in[2];
  const float* Whh0 = (const float*)d_in[3];
  const float* bih0 = (const float*)d_in[4];
  const float* bhh0 = (const float*)d_in[5];
  const float* Wih1 = (const float*)d_in[6];
  const float* Whh1 = (const float*)d_in[7];
  const float* bih1 = (const float*)d_in[8];
  const float* bhh1 = (const float*)d_in[9];
  const float* Wo   = (const float*)d_in[10];
  const float* bo   = (const float*)d_in[11];
  unsigned short* ws = (unsigned short*)d_ws;

  int total = WFRAG_ELEMS + WOUT_ELEMS + 1024 + 16 + 1024;
  int blocks = (total + 511) / 512;
  hipLaunchKernelGGL(setup_kernel, dim3(blocks), dim3(512), 0, stream,
                     Wih0, Whh0, bih0, bhh0, Wih1, Whh1, bih1, bhh1, Wo, bo, ws);

  const unsigned short* wfrag  = ws;
  const unsigned short* woutf  = ws + WFRAG_ELEMS;
  const unsigned short* biasbf = ws + BBF16_U16OFF;
  const float* boutc = reinterpret_cast<const float*>(ws) + BOUT_F32OFF;

  hipLaunchKernelGGL(lstm_kernel, dim3(NBATCH / ROWS), dim3(512), 0, stream,
                     ench, encc, wfrag, woutf, biasbf, boutc, (float*)d_out);
}

// Round 12
// 815.359 us; speedup vs baseline: 2.9810x; 1.0560x over previous
//
#include <hip/hip_runtime.h>
#include <hip/hip_bf16.h>

typedef __attribute__((ext_vector_type(8))) short bf16x8;
typedef __attribute__((ext_vector_type(4))) float f32x4;

#define NBATCH 4096
#define SEQT 181
#define NFEAT 12
#define HDIM 128
#define ROWS 16
#define LSTR 136              // padded bf16 row stride (272B: 16B-aligned, 2-way bank = free)
#define OUTSTRIDE (SEQT*NFEAT)

// d_ws layout (ushort units):
#define WFRAG_ELEMS 262144
#define WOUT_ELEMS  4096
#define BIAS_F32OFF (532480/4)     // f32 index (legacy, unused by cells)
#define BOUT_F32OFF (536576/4)     // f32 index (pre-scaled by -log2e)
#define BBF16_U16OFF 268320        // bf16-packed PRE-SCALED bias [l][wave][lg][16]

// LDS byte offsets: [0,131072) weight tail frags (s=6,7); act 6 bufs; bias bf16; bout
#define ACT_OFF  131072
#define BIAS_OFF 157184            // 2KB used (bf16-packed bias)
#define BOUT_OFF 161280
#define SMEM_BYTES 161344

#define SSIG (-1.442695041f)       // sigmoid pre-scale: sig(x) = rcp(1+exp2(SSIG*x))
#define STANH (-2.885390082f)      // tanh pre-scale: e = exp2(STANH*x) -> (1-e)/(1+e)

// fast barrier: LDS-visibility only (skip vmcnt drain -- wave0's out-proj
// global ops need no cross-wave ordering)
#define FBAR() asm volatile("s_waitcnt lgkmcnt(0)\n\ts_barrier" ::: "memory")

__device__ __forceinline__ float fsig2(float xs) {   // xs already scaled by SSIG
  return __builtin_amdgcn_rcpf(1.0f + __builtin_amdgcn_exp2f(xs));
}
__device__ __forceinline__ unsigned short f2bf(float x) {
  __hip_bfloat16 h = __float2bfloat16(x);
  return __builtin_bit_cast(unsigned short, h);
}

// ---------------- setup: repack weights into MFMA fragment order (bf16), pre-scaled ----------------
__global__ void setup_kernel(const float* __restrict__ Wih0, const float* __restrict__ Whh0,
                             const float* __restrict__ bih0, const float* __restrict__ bhh0,
                             const float* __restrict__ Wih1, const float* __restrict__ Whh1,
                             const float* __restrict__ bih1, const float* __restrict__ bhh1,
                             const float* __restrict__ Wo,   const float* __restrict__ bo,
                             unsigned short* __restrict__ ws)
{
  int idx = blockIdx.x * blockDim.x + threadIdx.x;
  if (idx < WFRAG_ELEMS) {
    // A-frag (weights): lane&15 = gate-dim, k=(lane>>4)*8+e over [x(128)|h(128)]
    int e = idx & 7, lane = (idx >> 3) & 63, s = (idx >> 9) & 7, g = (idx >> 12) & 3,
        w = (idx >> 14) & 7, l = idx >> 17;
    int row = g * 128 + w * 16 + (lane & 15);
    int k   = s * 32 + (lane >> 4) * 8 + e;
    const float* Wih = l ? Wih1 : Wih0;
    const float* Whh = l ? Whh1 : Whh0;
    float v = (k < HDIM) ? Wih[row * HDIM + k] : Whh[row * HDIM + (k - HDIM)];
    float sc = (g == 2) ? STANH : SSIG;          // gate g uses tanh, others sigmoid
    ws[idx] = f2bf(v * sc);
  } else if (idx < WFRAG_ELEMS + WOUT_ELEMS) {
    int i2 = idx - WFRAG_ELEMS;
    int e = i2 & 7, lane = (i2 >> 3) & 63, s = i2 >> 9;
    int c = lane & 15;
    int k = s * 32 + (lane >> 4) * 8 + e;           // k over [z0(128) | z1(128)]
    float v = (c < NFEAT) ? Wo[c * 256 + k] * SSIG : 0.0f;
    ws[idx] = f2bf(v);
  } else if (idx < WFRAG_ELEMS + WOUT_ELEMS + 1024) {
    int i3 = idx - (WFRAG_ELEMS + WOUT_ELEMS);
    int l = i3 >> 9, r = i3 & 511;
    float v = l ? (bih1[r] + bhh1[r]) : (bih0[r] + bhh0[r]);
    reinterpret_cast<float*>(ws)[BIAS_F32OFF + i3] = v;   // legacy, unused
  } else if (idx < WFRAG_ELEMS + WOUT_ELEMS + 1024 + 16) {
    int i4 = idx - (WFRAG_ELEMS + WOUT_ELEMS + 1024);
    reinterpret_cast<float*>(ws)[BOUT_F32OFF + i4] = (i4 < NFEAT) ? bo[i4] * SSIG : 0.0f;
  } else if (idx < WFRAG_ELEMS + WOUT_ELEMS + 1024 + 16 + 1024) {
    // bf16-packed bias (pre-scaled): [l][wave][lg][16]
    int i5 = idx - (WFRAG_ELEMS + WOUT_ELEMS + 1024 + 16);
    int l = i5 >> 9, r = i5 & 511;
    int w = r >> 6, lg = (r >> 4) & 3, j16 = r & 15;
    int f = j16 >> 3, j = j16 & 7;
    int gate = f * 2 + (j >> 2);
    int dim  = w * 16 + lg * 4 + (j & 3);
    float v = l ? (bih1[gate * 128 + dim] + bhh1[gate * 128 + dim])
                : (bih0[gate * 128 + dim] + bhh0[gate * 128 + dim]);
    float sc = (gate == 2) ? STANH : SSIG;
    ws[BBF16_U16OFF + i5] = f2bf(v * sc);
  }
}

// ---------------- main: 256 blocks x 512 threads ------------------------------------
// R12 = R11 + pre-scaled gate weights (kills per-activation scale muls) +
// shared-rcp activation algebra (10 -> 8 transcendentals per element, exact).
__global__ void
__attribute__((amdgpu_flat_work_group_size(512, 512), amdgpu_waves_per_eu(2, 2)))
lstm_kernel(
    const float* __restrict__ ench, const float* __restrict__ encc,
    const unsigned short* __restrict__ wfrag, const unsigned short* __restrict__ woutf,
    const unsigned short* __restrict__ biasbf, const float* __restrict__ boutc,
    float* __restrict__ out)
{
  __shared__ __align__(16) unsigned char smem[SMEM_BYTES];
  bf16x8* wlds = reinterpret_cast<bf16x8*>(smem);
  unsigned short* act = reinterpret_cast<unsigned short*>(smem + ACT_OFF);

  const int tid  = threadIdx.x;
  const int wave = tid >> 6, lane = tid & 63;
  const int col  = lane & 15, lg = lane >> 4;
  const int n0   = blockIdx.x * ROWS;
  const int dbase = wave * 16 + lg * 4;

  const bf16x8* wfv = reinterpret_cast<const bf16x8*>(wfrag);

  // ---- persistent weight fragments: s=0..5 in registers (pinned chunk-by-chunk,
  //      fenced so the scheduler can't cluster all 48 loads into one pressure spike)
  bf16x8 wreg[2][4][6];
  #pragma unroll
  for (int l = 0; l < 2; ++l)
    #pragma unroll
    for (int g = 0; g < 4; ++g) {
      #pragma unroll
      for (int s = 0; s < 6; ++s)
        wreg[l][g][s] = wfv[(size_t)((((l * 8 + wave) * 4 + g) * 8) + s) * 64 + lane];
      #pragma unroll
      for (int s = 0; s < 6; ++s) {
        f32x4 t_ = __builtin_bit_cast(f32x4, wreg[l][g][s]);
        asm volatile("" : "+v"(t_));            // opaque: no remat, value must stay live
        wreg[l][g][s] = __builtin_bit_cast(bf16x8, t_);
      }
      __builtin_amdgcn_sched_barrier(0);        // fence: next chunk can't be hoisted up
    }

  // ---- s=6..7 fragments -> LDS (16/wave, 128 KiB total) ----
  #pragma unroll
  for (int l = 0; l < 2; ++l)
    #pragma unroll
    for (int g = 0; g < 4; ++g)
      #pragma unroll
      for (int si = 0; si < 2; ++si)
        wlds[(((wave * 2 + l) * 4 + g) * 2 + si) * 64 + lane] =
            wfv[(size_t)((((l * 8 + wave) * 4 + g) * 8) + 6 + si) * 64 + lane];

  // zero x-ping buffers 0,1 (dec_in0 = 0)
  for (int i = tid; i < 2 * ROWS * LSTR; i += 512) act[i] = 0;
  // initial h layer0 -> buf5 ; initial h layer1 -> buf3 (read once by L1t0 at t=0,
  // then overwritten by L1t1(t=0) which runs after that read -- no race)
  for (int i = tid; i < ROWS * HDIM; i += 512) {
    int r = i >> 7, d = i & (HDIM - 1);
    act[(5 * ROWS + r) * LSTR + d] = f2bf(ench[(n0 + r) * HDIM + d]);
    act[(3 * ROWS + r) * LSTR + d] = f2bf(ench[(size_t)(NBATCH + n0 + r) * HDIM + d]);
  }
  // bf16-packed bias -> LDS (1024 ushorts = 2KB)
  for (int i = tid; i < 1024; i += 512)
    reinterpret_cast<unsigned short*>(smem + BIAS_OFF)[i] = biasbf[i];
  if (tid < 16) reinterpret_cast<float*>(smem + BOUT_OFF)[tid] = boutc[tid];
  // c-state: lane holds batch n0+col, dims dbase..dbase+3
  f32x4 c0 = *reinterpret_cast<const f32x4*>(&encc[(size_t)(n0 + col) * HDIM + dbase]);
  f32x4 c1 = *reinterpret_cast<const f32x4*>(&encc[(size_t)(NBATCH + n0 + col) * HDIM + dbase]);
  __syncthreads();   // init barrier: full drain (global staging must be visible)

  const int aoffl = col * LSTR + lg * 8;

  // streamed cell; bias from 2 broadcast b128 LDS reads (bf16<<16 = exact f32).
  // Activation tail (pre-scaled accs, shared-rcp, exact algebra):
  //   acc0=SSIG*i  acc1=SSIG*f  acc2=STANH*g  acc3=SSIG*o
  //   sig(f)=rcp(1+Ef) ; sig(i)*tanh(g)=(1-Eg)*rcp((1+Ei)(1+Eg))
  //   sig(o)*tanh(cn)=(1-Ec)*rcp((1+Eo)(1+Ec)), Ec=exp2(STANH*cn)
  auto cell = [&](int xb, int hb, int ob, const bf16x8 (&wr)[4][6], int lb, int bl, f32x4& c) {
    const unsigned short* xp = act + xb * (ROWS * LSTR) + aoffl;
    const unsigned short* hp = act + hb * (ROWS * LSTR) + aoffl;
    const unsigned char* bptr = smem + BIAS_OFF + (size_t)(((bl * 8 + wave) * 4 + lg) * 32);
    bf16x8 bb0 = *reinterpret_cast<const bf16x8*>(bptr);
    bf16x8 bb1 = *reinterpret_cast<const bf16x8*>(bptr + 16);
    f32x4 acc0, acc1, acc2, acc3;
    #pragma unroll
    for (int j = 0; j < 4; ++j) {
      acc0[j] = __builtin_bit_cast(float, ((unsigned)(unsigned short)bb0[j]) << 16);
      acc1[j] = __builtin_bit_cast(float, ((unsigned)(unsigned short)bb0[4 + j]) << 16);
      acc2[j] = __builtin_bit_cast(float, ((unsigned)(unsigned short)bb1[j]) << 16);
      acc3[j] = __builtin_bit_cast(float, ((unsigned)(unsigned short)bb1[4 + j]) << 16);
    }
    #pragma unroll
    for (int s = 0; s < 4; ++s) {                       // k = x-half (reg weights)
      bf16x8 b = *reinterpret_cast<const bf16x8*>(&xp[s * 32]);
      acc0 = __builtin_amdgcn_mfma_f32_16x16x32_bf16(wr[0][s], b, acc0, 0, 0, 0);
      acc1 = __builtin_amdgcn_mfma_f32_16x16x32_bf16(wr[1][s], b, acc1, 0, 0, 0);
      acc2 = __builtin_amdgcn_mfma_f32_16x16x32_bf16(wr[2][s], b, acc2, 0, 0, 0);
      acc3 = __builtin_amdgcn_mfma_f32_16x16x32_bf16(wr[3][s], b, acc3, 0, 0, 0);
    }
    #pragma unroll
    for (int s = 0; s < 2; ++s) {                       // k = h-half, reg weights
      bf16x8 b = *reinterpret_cast<const bf16x8*>(&hp[s * 32]);
      acc0 = __builtin_amdgcn_mfma_f32_16x16x32_bf16(wr[0][4 + s], b, acc0, 0, 0, 0);
      acc1 = __builtin_amdgcn_mfma_f32_16x16x32_bf16(wr[1][4 + s], b, acc1, 0, 0, 0);
      acc2 = __builtin_amdgcn_mfma_f32_16x16x32_bf16(wr[2][4 + s], b, acc2, 0, 0, 0);
      acc3 = __builtin_amdgcn_mfma_f32_16x16x32_bf16(wr[3][4 + s], b, acc3, 0, 0, 0);
    }
    #pragma unroll
    for (int si = 0; si < 2; ++si) {                    // k = h-half tail, LDS weights
      bf16x8 b = *reinterpret_cast<const bf16x8*>(&hp[(2 + si) * 32]);
      bf16x8 w0 = wlds[(lb + 0 * 2 + si) * 64 + lane];
      bf16x8 w1 = wlds[(lb + 1 * 2 + si) * 64 + lane];
      bf16x8 w2 = wlds[(lb + 2 * 2 + si) * 64 + lane];
      bf16x8 w3 = wlds[(lb + 3 * 2 + si) * 64 + lane];
      acc0 = __builtin_amdgcn_mfma_f32_16x16x32_bf16(w0, b, acc0, 0, 0, 0);
      acc1 = __builtin_amdgcn_mfma_f32_16x16x32_bf16(w1, b, acc1, 0, 0, 0);
      acc2 = __builtin_amdgcn_mfma_f32_16x16x32_bf16(w2, b, acc2, 0, 0, 0);
      acc3 = __builtin_amdgcn_mfma_f32_16x16x32_bf16(w3, b, acc3, 0, 0, 0);
    }
    unsigned int hu[4];
    #pragma unroll
    for (int j = 0; j < 4; ++j) {
      float Ei = __builtin_amdgcn_exp2f(acc0[j]);
      float Ef = __builtin_amdgcn_exp2f(acc1[j]);
      float Eg = __builtin_amdgcn_exp2f(fminf(acc2[j], 80.0f));   // clamp: kill inf-inf NaN
      float Eo = __builtin_amdgcn_exp2f(acc3[j]);
      float sf = __builtin_amdgcn_rcpf(1.0f + Ef);
      float rig = __builtin_amdgcn_rcpf((1.0f + Ei) * (1.0f + Eg));
      float cn = __builtin_fmaf(c[j], sf, (1.0f - Eg) * rig);
      c[j] = cn;
      float Ec = __builtin_amdgcn_exp2f(fminf(STANH * cn, 80.0f));
      float rr = __builtin_amdgcn_rcpf((1.0f + Eo) * (1.0f + Ec));
      hu[j] = f2bf((1.0f - Ec) * rr);
    }
    uint2* op = reinterpret_cast<uint2*>(act + ob * (ROWS * LSTR) + col * LSTR + dbase);
    *op = make_uint2(hu[0] | (hu[1] << 16), hu[2] | (hu[3] << 16));
    FBAR();
  };

  const int lb0 = (wave * 2 + 0) * 8;
  const int lb1 = (wave * 2 + 1) * 8;
  const bf16x8* wov = reinterpret_cast<const bf16x8*>(woutf);

  for (int t = 0; t < SEQT; ++t) {
    const int xA = (t & 1) ? 2 : 0, xB = xA + 1;
    const int zA = (t & 1) ? 0 : 2, zB = zA + 1;
    cell(xA, 5, 4, wreg[0], lb0, 0, c0);               // L0 t0
    cell(xB, 4, 5, wreg[0], lb0, 0, c0);               // L0 t1
    cell(4, (t == 0) ? 3 : xB, zA, wreg[1], lb1, 1, c1); // L1 t0 (t=0: h1 staged in buf3)
    cell(5, zA, zB, wreg[1], lb1, 1, c1);              // L1 t1
    if (wave == 0) {                                   // output projection (one tile)
      const unsigned short* z0 = act + zA * (ROWS * LSTR) + aoffl;
      const unsigned short* z1 = act + zB * (ROWS * LSTR) + aoffl;
      f32x4 po = *reinterpret_cast<const f32x4*>(smem + BOUT_OFF + lg * 16);
      #pragma unroll
      for (int s = 0; s < 4; ++s) {
        bf16x8 z = *reinterpret_cast<const bf16x8*>(&z0[s * 32]);
        po = __builtin_amdgcn_mfma_f32_16x16x32_bf16(wov[s * 64 + lane], z, po, 0, 0, 0);
      }
      #pragma unroll
      for (int s = 0; s < 4; ++s) {
        bf16x8 z = *reinterpret_cast<const bf16x8*>(&z1[s * 32]);
        po = __builtin_amdgcn_mfma_f32_16x16x32_bf16(wov[(4 + s) * 64 + lane], z, po, 0, 0, 0);
      }
      if (lg < 3) {
        f32x4 r;
        r[0] = fsig2(po[0]); r[1] = fsig2(po[1]); r[2] = fsig2(po[2]); r[3] = fsig2(po[3]);
        *reinterpret_cast<f32x4*>(&out[(size_t)(n0 + col) * OUTSTRIDE + t * NFEAT + lg * 4]) = r;
      }
    }
  }
}

extern "C" void kernel_launch(void* const* d_in, const int* in_sizes, int n_in,
                              void* d_out, int out_size, void* d_ws, size_t ws_size,
                              hipStream_t stream) {
  const float* ench = (const float*)d_in[0];
  const float* encc = (const float*)d_in[1];
  const float* Wih0 = (const float*)d_in[2];
  const float* Whh0 = (const float*)d_in[3];
  const float* bih0 = (const float*)d_in[4];
  const float* bhh0 = (const float*)d_in[5];
  const float* Wih1 = (const float*)d_in[6];
  const float* Whh1 = (const float*)d_in[7];
  const float* bih1 = (const float*)d_in[8];
  const float* bhh1 = (const float*)d_in[9];
  const float* Wo   = (const float*)d_in[10];
  const float* bo   = (const float*)d_in[11];
  unsigned short* ws = (unsigned short*)d_ws;

  int total = WFRAG_ELEMS + WOUT_ELEMS + 1024 + 16 + 1024;
  int blocks = (total + 511) / 512;
  hipLaunchKernelGGL(setup_kernel, dim3(blocks), dim3(512), 0, stream,
                     Wih0, Whh0, bih0, bhh0, Wih1, Whh1, bih1, bhh1, Wo, bo, ws);

  const unsigned short* wfrag  = ws;
  const unsigned short* woutf  = ws + WFRAG_ELEMS;
  const unsigned short* biasbf = ws + BBF16_U16OFF;
  const float* boutc = reinterpret_cast<const float*>(ws) + BOUT_F32OFF;

  hipLaunchKernelGGL(lstm_kernel, dim3(NBATCH / ROWS), dim3(512), 0, stream,
                     ench, encc, wfrag, woutf, biasbf, boutc, (float*)d_out);
}

// Round 13
// 790.889 us; speedup vs baseline: 3.0732x; 1.0309x over previous
//
#include <hip/hip_runtime.h>
#include <hip/hip_bf16.h>

typedef __attribute__((ext_vector_type(8))) short bf16x8;
typedef __attribute__((ext_vector_type(4))) float f32x4;

#define NBATCH 4096
#define SEQT 181
#define NFEAT 12
#define HDIM 128
#define ROWS 16
#define LSTR 136              // padded bf16 row stride
#define OUTSTRIDE (SEQT*NFEAT)

// d_ws layout (ushort units):
#define WFRAG_ELEMS 262144
#define WOUT_ELEMS  4096
#define BIAS_F32OFF (532480/4)     // legacy, unused
#define BOUT_F32OFF (536576/4)     // pre-scaled by -log2e
#define BBF16_U16OFF 268320        // bf16-packed PRE-SCALED bias [l][wave][lg][16]

// LDS byte offsets
#define ACT_OFF  131072
#define BIAS_OFF 157184
#define BOUT_OFF 161280
#define SMEM_BYTES 161344

#define SSIG (-1.442695041f)
#define STANH (-2.885390082f)

#define FBAR() asm volatile("s_waitcnt lgkmcnt(0)\n\ts_barrier" ::: "memory")

__device__ __forceinline__ float fsig2(float xs) {
  return __builtin_amdgcn_rcpf(1.0f + __builtin_amdgcn_exp2f(xs));
}
__device__ __forceinline__ unsigned short f2bf(float x) {
  __hip_bfloat16 h = __float2bfloat16(x);
  return __builtin_bit_cast(unsigned short, h);
}

// ---------------- setup: repack weights into MFMA fragment order (bf16), pre-scaled ----------------
__global__ void setup_kernel(const float* __restrict__ Wih0, const float* __restrict__ Whh0,
                             const float* __restrict__ bih0, const float* __restrict__ bhh0,
                             const float* __restrict__ Wih1, const float* __restrict__ Whh1,
                             const float* __restrict__ bih1, const float* __restrict__ bhh1,
                             const float* __restrict__ Wo,   const float* __restrict__ bo,
                             unsigned short* __restrict__ ws)
{
  int idx = blockIdx.x * blockDim.x + threadIdx.x;
  if (idx < WFRAG_ELEMS) {
    int e = idx & 7, lane = (idx >> 3) & 63, s = (idx >> 9) & 7, g = (idx >> 12) & 3,
        w = (idx >> 14) & 7, l = idx >> 17;
    int row = g * 128 + w * 16 + (lane & 15);
    int k   = s * 32 + (lane >> 4) * 8 + e;
    const float* Wih = l ? Wih1 : Wih0;
    const float* Whh = l ? Whh1 : Whh0;
    float v = (k < HDIM) ? Wih[row * HDIM + k] : Whh[row * HDIM + (k - HDIM)];
    float sc = (g == 2) ? STANH : SSIG;
    ws[idx] = f2bf(v * sc);
  } else if (idx < WFRAG_ELEMS + WOUT_ELEMS) {
    int i2 = idx - WFRAG_ELEMS;
    int e = i2 & 7, lane = (i2 >> 3) & 63, s = i2 >> 9;
    int c = lane & 15;
    int k = s * 32 + (lane >> 4) * 8 + e;
    float v = (c < NFEAT) ? Wo[c * 256 + k] * SSIG : 0.0f;
    ws[idx] = f2bf(v);
  } else if (idx < WFRAG_ELEMS + WOUT_ELEMS + 1024) {
    int i3 = idx - (WFRAG_ELEMS + WOUT_ELEMS);
    int l = i3 >> 9, r = i3 & 511;
    float v = l ? (bih1[r] + bhh1[r]) : (bih0[r] + bhh0[r]);
    reinterpret_cast<float*>(ws)[BIAS_F32OFF + i3] = v;
  } else if (idx < WFRAG_ELEMS + WOUT_ELEMS + 1024 + 16) {
    int i4 = idx - (WFRAG_ELEMS + WOUT_ELEMS + 1024);
    reinterpret_cast<float*>(ws)[BOUT_F32OFF + i4] = (i4 < NFEAT) ? bo[i4] * SSIG : 0.0f;
  } else if (idx < WFRAG_ELEMS + WOUT_ELEMS + 1024 + 16 + 1024) {
    int i5 = idx - (WFRAG_ELEMS + WOUT_ELEMS + 1024 + 16);
    int l = i5 >> 9, r = i5 & 511;
    int w = r >> 6, lg = (r >> 4) & 3, j16 = r & 15;
    int f = j16 >> 3, j = j16 & 7;
    int gate = f * 2 + (j >> 2);
    int dim  = w * 16 + lg * 4 + (j & 3);
    float v = l ? (bih1[gate * 128 + dim] + bhh1[gate * 128 + dim])
                : (bih0[gate * 128 + dim] + bhh0[gate * 128 + dim]);
    float sc = (gate == 2) ? STANH : SSIG;
    ws[BBF16_U16OFF + i5] = f2bf(v * sc);
  }
}

// ---------------- main: 256 blocks x 512 threads ------------------------------------
// R13 = R12 + cell-pairing: the 4-cell step contains two independent pairs
//   B(t) = {L0t1(t), L1t0(t)}   (both read buf4/xB; write buf5/zA -- disjoint)
//   A(t) = {L1t1(t), L0t0(t+1)} (both read buf5/zA; write zB/buf4 -- disjoint)
// -> one barrier per PAIR: 363 barriers total instead of 724. sched_barrier(0)
// between paired cells keeps transient register pressure = one cell (no spill).
__global__ void
__attribute__((amdgpu_flat_work_group_size(512, 512), amdgpu_waves_per_eu(2, 2)))
lstm_kernel(
    const float* __restrict__ ench, const float* __restrict__ encc,
    const unsigned short* __restrict__ wfrag, const unsigned short* __restrict__ woutf,
    const unsigned short* __restrict__ biasbf, const float* __restrict__ boutc,
    float* __restrict__ out)
{
  __shared__ __align__(16) unsigned char smem[SMEM_BYTES];
  bf16x8* wlds = reinterpret_cast<bf16x8*>(smem);
  unsigned short* act = reinterpret_cast<unsigned short*>(smem + ACT_OFF);

  const int tid  = threadIdx.x;
  const int wave = tid >> 6, lane = tid & 63;
  const int col  = lane & 15, lg = lane >> 4;
  const int n0   = blockIdx.x * ROWS;
  const int dbase = wave * 16 + lg * 4;

  const bf16x8* wfv = reinterpret_cast<const bf16x8*>(wfrag);

  // ---- persistent weight fragments: s=0..5 pinned chunk-by-chunk (R8 recipe) ----
  bf16x8 wreg[2][4][6];
  #pragma unroll
  for (int l = 0; l < 2; ++l)
    #pragma unroll
    for (int g = 0; g < 4; ++g) {
      #pragma unroll
      for (int s = 0; s < 6; ++s)
        wreg[l][g][s] = wfv[(size_t)((((l * 8 + wave) * 4 + g) * 8) + s) * 64 + lane];
      #pragma unroll
      for (int s = 0; s < 6; ++s) {
        f32x4 t_ = __builtin_bit_cast(f32x4, wreg[l][g][s]);
        asm volatile("" : "+v"(t_));
        wreg[l][g][s] = __builtin_bit_cast(bf16x8, t_);
      }
      __builtin_amdgcn_sched_barrier(0);
    }

  // ---- s=6..7 fragments -> LDS ----
  #pragma unroll
  for (int l = 0; l < 2; ++l)
    #pragma unroll
    for (int g = 0; g < 4; ++g)
      #pragma unroll
      for (int si = 0; si < 2; ++si)
        wlds[(((wave * 2 + l) * 4 + g) * 2 + si) * 64 + lane] =
            wfv[(size_t)((((l * 8 + wave) * 4 + g) * 8) + 6 + si) * 64 + lane];

  // zero x-ping buffers 0,1 (dec_in0 = 0)
  for (int i = tid; i < 2 * ROWS * LSTR; i += 512) act[i] = 0;
  // initial h0 -> buf5 ; initial h1 -> buf3 (read once by L1t0(0), overwritten later)
  for (int i = tid; i < ROWS * HDIM; i += 512) {
    int r = i >> 7, d = i & (HDIM - 1);
    act[(5 * ROWS + r) * LSTR + d] = f2bf(ench[(n0 + r) * HDIM + d]);
    act[(3 * ROWS + r) * LSTR + d] = f2bf(ench[(size_t)(NBATCH + n0 + r) * HDIM + d]);
  }
  for (int i = tid; i < 1024; i += 512)
    reinterpret_cast<unsigned short*>(smem + BIAS_OFF)[i] = biasbf[i];
  if (tid < 16) reinterpret_cast<float*>(smem + BOUT_OFF)[tid] = boutc[tid];
  f32x4 c0 = *reinterpret_cast<const f32x4*>(&encc[(size_t)(n0 + col) * HDIM + dbase]);
  f32x4 c1 = *reinterpret_cast<const f32x4*>(&encc[(size_t)(NBATCH + n0 + col) * HDIM + dbase]);
  __syncthreads();   // init barrier: full drain

  const int aoffl = col * LSTR + lg * 8;

  // streamed cell WITHOUT trailing barrier (barriers are per-pair in the loop)
  auto cellNB = [&](int xb, int hb, int ob, const bf16x8 (&wr)[4][6], int lb, int bl, f32x4& c) {
    const unsigned short* xp = act + xb * (ROWS * LSTR) + aoffl;
    const unsigned short* hp = act + hb * (ROWS * LSTR) + aoffl;
    const unsigned char* bptr = smem + BIAS_OFF + (size_t)(((bl * 8 + wave) * 4 + lg) * 32);
    bf16x8 bb0 = *reinterpret_cast<const bf16x8*>(bptr);
    bf16x8 bb1 = *reinterpret_cast<const bf16x8*>(bptr + 16);
    f32x4 acc0, acc1, acc2, acc3;
    #pragma unroll
    for (int j = 0; j < 4; ++j) {
      acc0[j] = __builtin_bit_cast(float, ((unsigned)(unsigned short)bb0[j]) << 16);
      acc1[j] = __builtin_bit_cast(float, ((unsigned)(unsigned short)bb0[4 + j]) << 16);
      acc2[j] = __builtin_bit_cast(float, ((unsigned)(unsigned short)bb1[j]) << 16);
      acc3[j] = __builtin_bit_cast(float, ((unsigned)(unsigned short)bb1[4 + j]) << 16);
    }
    #pragma unroll
    for (int s = 0; s < 4; ++s) {                       // k = x-half (reg weights)
      bf16x8 b = *reinterpret_cast<const bf16x8*>(&xp[s * 32]);
      acc0 = __builtin_amdgcn_mfma_f32_16x16x32_bf16(wr[0][s], b, acc0, 0, 0, 0);
      acc1 = __builtin_amdgcn_mfma_f32_16x16x32_bf16(wr[1][s], b, acc1, 0, 0, 0);
      acc2 = __builtin_amdgcn_mfma_f32_16x16x32_bf16(wr[2][s], b, acc2, 0, 0, 0);
      acc3 = __builtin_amdgcn_mfma_f32_16x16x32_bf16(wr[3][s], b, acc3, 0, 0, 0);
    }
    #pragma unroll
    for (int s = 0; s < 2; ++s) {                       // k = h-half, reg weights
      bf16x8 b = *reinterpret_cast<const bf16x8*>(&hp[s * 32]);
      acc0 = __builtin_amdgcn_mfma_f32_16x16x32_bf16(wr[0][4 + s], b, acc0, 0, 0, 0);
      acc1 = __builtin_amdgcn_mfma_f32_16x16x32_bf16(wr[1][4 + s], b, acc1, 0, 0, 0);
      acc2 = __builtin_amdgcn_mfma_f32_16x16x32_bf16(wr[2][4 + s], b, acc2, 0, 0, 0);
      acc3 = __builtin_amdgcn_mfma_f32_16x16x32_bf16(wr[3][4 + s], b, acc3, 0, 0, 0);
    }
    #pragma unroll
    for (int si = 0; si < 2; ++si) {                    // k = h-half tail, LDS weights
      bf16x8 b = *reinterpret_cast<const bf16x8*>(&hp[(2 + si) * 32]);
      bf16x8 w0 = wlds[(lb + 0 * 2 + si) * 64 + lane];
      bf16x8 w1 = wlds[(lb + 1 * 2 + si) * 64 + lane];
      bf16x8 w2 = wlds[(lb + 2 * 2 + si) * 64 + lane];
      bf16x8 w3 = wlds[(lb + 3 * 2 + si) * 64 + lane];
      acc0 = __builtin_amdgcn_mfma_f32_16x16x32_bf16(w0, b, acc0, 0, 0, 0);
      acc1 = __builtin_amdgcn_mfma_f32_16x16x32_bf16(w1, b, acc1, 0, 0, 0);
      acc2 = __builtin_amdgcn_mfma_f32_16x16x32_bf16(w2, b, acc2, 0, 0, 0);
      acc3 = __builtin_amdgcn_mfma_f32_16x16x32_bf16(w3, b, acc3, 0, 0, 0);
    }
    unsigned int hu[4];
    #pragma unroll
    for (int j = 0; j < 4; ++j) {
      float Ei = __builtin_amdgcn_exp2f(acc0[j]);
      float Ef = __builtin_amdgcn_exp2f(acc1[j]);
      float Eg = __builtin_amdgcn_exp2f(fminf(acc2[j], 80.0f));
      float Eo = __builtin_amdgcn_exp2f(acc3[j]);
      float sf = __builtin_amdgcn_rcpf(1.0f + Ef);
      float rig = __builtin_amdgcn_rcpf((1.0f + Ei) * (1.0f + Eg));
      float cn = __builtin_fmaf(c[j], sf, (1.0f - Eg) * rig);
      c[j] = cn;
      float Ec = __builtin_amdgcn_exp2f(fminf(STANH * cn, 80.0f));
      float rr = __builtin_amdgcn_rcpf((1.0f + Eo) * (1.0f + Ec));
      hu[j] = f2bf((1.0f - Ec) * rr);
    }
    uint2* op = reinterpret_cast<uint2*>(act + ob * (ROWS * LSTR) + col * LSTR + dbase);
    *op = make_uint2(hu[0] | (hu[1] << 16), hu[2] | (hu[3] << 16));
  };

  const int lb0 = (wave * 2 + 0) * 8;
  const int lb1 = (wave * 2 + 1) * 8;
  const bf16x8* wov = reinterpret_cast<const bf16x8*>(woutf);

  // out-projection for step tt, reading z halves from bufs b0,b1 (wave0 only)
  auto outproj = [&](int b0, int b1, int tt) {
    const unsigned short* z0 = act + b0 * (ROWS * LSTR) + aoffl;
    const unsigned short* z1 = act + b1 * (ROWS * LSTR) + aoffl;
    f32x4 po = *reinterpret_cast<const f32x4*>(smem + BOUT_OFF + lg * 16);
    #pragma unroll
    for (int s = 0; s < 4; ++s) {
      bf16x8 z = *reinterpret_cast<const bf16x8*>(&z0[s * 32]);
      po = __builtin_amdgcn_mfma_f32_16x16x32_bf16(wov[s * 64 + lane], z, po, 0, 0, 0);
    }
    #pragma unroll
    for (int s = 0; s < 4; ++s) {
      bf16x8 z = *reinterpret_cast<const bf16x8*>(&z1[s * 32]);
      po = __builtin_amdgcn_mfma_f32_16x16x32_bf16(wov[(4 + s) * 64 + lane], z, po, 0, 0, 0);
    }
    if (lg < 3) {
      f32x4 r;
      r[0] = fsig2(po[0]); r[1] = fsig2(po[1]); r[2] = fsig2(po[2]); r[3] = fsig2(po[3]);
      *reinterpret_cast<f32x4*>(&out[(size_t)(n0 + col) * OUTSTRIDE + tt * NFEAT + lg * 4]) = r;
    }
  };

  // prologue: L0t0(0)  (x=buf0 zeros, h=buf5)
  cellNB(0, 5, 4, wreg[0], lb0, 0, c0);
  FBAR();

  for (int t = 0; t < SEQT; ++t) {
    const int xA = (t & 1) ? 2 : 0, xB = xA + 1;
    const int zA = (t & 1) ? 0 : 2, zB = zA + 1;
    // ---- pair B(t): L0t1(t) || L1t0(t)  (+ out-proj(t-1) on wave0) ----
    cellNB(xB, 4, 5, wreg[0], lb0, 0, c0);            // L0t1: x=xB, h=buf4 -> buf5
    __builtin_amdgcn_sched_barrier(0);
    cellNB(4, (t == 0) ? 3 : xB, zA, wreg[1], lb1, 1, c1);  // L1t0: x=buf4 -> zA
    if (wave == 0 && t > 0) outproj(xA, xB, t - 1);   // zA(t-1)=xA, zB(t-1)=xB
    FBAR();
    // ---- pair A(t): L1t1(t) || L0t0(t+1) ----
    cellNB(5, zA, zB, wreg[1], lb1, 1, c1);           // L1t1: x=buf5, h=zA -> zB
    __builtin_amdgcn_sched_barrier(0);
    if (t + 1 < SEQT)
      cellNB(zA, 5, 4, wreg[0], lb0, 0, c0);          // L0t0(t+1): x=zA, h=buf5 -> buf4
    FBAR();
  }
  // epilogue: out-proj(180); zA(180)=2, zB(180)=3 (t=180 even), still intact
  if (wave == 0) outproj(2, 3, SEQT - 1);
}

extern "C" void kernel_launch(void* const* d_in, const int* in_sizes, int n_in,
                              void* d_out, int out_size, void* d_ws, size_t ws_size,
                              hipStream_t stream) {
  const float* ench = (const float*)d_in[0];
  const float* encc = (const float*)d_in[1];
  const float* Wih0 = (const float*)d_in[2];
  const float* Whh0 = (const float*)d_in[3];
  const float* bih0 = (const float*)d_in[4];
  const float* bhh0 = (const float*)d_in[5];
  const float* Wih1 = (const float*)d_in[6];
  const float* Whh1 = (const float*)d_in[7];
  const float* bih1 = (const float*)d_in[8];
  const float* bhh1 = (const float*)d_in[9];
  const float* Wo   = (const float*)d_in[10];
  const float* bo   = (const float*)d_in[11];
  unsigned short* ws = (unsigned short*)d_ws;

  int total = WFRAG_ELEMS + WOUT_ELEMS + 1024 + 16 + 1024;
  int blocks = (total + 511) / 512;
  hipLaunchKernelGGL(setup_kernel, dim3(blocks), dim3(512), 0, stream,
                     Wih0, Whh0, bih0, bhh0, Wih1, Whh1, bih1, bhh1, Wo, bo, ws);

  const unsigned short* wfrag  = ws;
  const unsigned short* woutf  = ws + WFRAG_ELEMS;
  const unsigned short* biasbf = ws + BBF16_U16OFF;
  const float* boutc = reinterpret_cast<const float*>(ws) + BOUT_F32OFF;

  hipLaunchKernelGGL(lstm_kernel, dim3(NBATCH / ROWS), dim3(512), 0, stream,
                     ench, encc, wfrag, woutf, biasbf, boutc, (float*)d_out);
}